// Round 2
// baseline (1186.839 us; speedup 1.0000x reference)
//
#include <hip/hip_runtime.h>
#include <hip/hip_bf16.h>

#define B_ 8
#define T_ 8192
#define M_ (B_ * T_)          // 65536 rows
#define IDIM 256
#define HDIM 1024
#define ODIM 256
#define CDIM 128
#define OUT_OFF ((size_t)M_ * ODIM)   // start of mask_new region in d_out

typedef __attribute__((ext_vector_type(4))) float floatx4;
typedef __attribute__((ext_vector_type(8))) short shortx8;

// ---------------------------------------------------------------------------
// K0: WdT[n][k] = bf16(W_dec_sel[k][n])
// ---------------------------------------------------------------------------
__global__ __launch_bounds__(256) void k0_convw(const float* __restrict__ Wself,
                                                const float* __restrict__ Wsrc,
                                                const int* __restrict__ dtype,
                                                __hip_bfloat16* __restrict__ WdT) {
    int id = blockIdx.x * 256 + threadIdx.x;
    int n = id >> 10;
    int k = id & 1023;
    const float* W = (*dtype == 0) ? Wself : Wsrc;
    WdT[id] = __float2bfloat16(W[(size_t)k * ODIM + n]);
}

// ---------------------------------------------------------------------------
// K1: encoder GEMM fp32 (must be fp32: top-k selection sensitivity).
// BM=128 BN=128 BK=32, 256 threads, 8x8 micro-tile, register prefetch of the
// next global tile across the compute phase.
// ---------------------------------------------------------------------------
__global__ __launch_bounds__(256) void k1_enc(const float* __restrict__ X,
                                              const float* __restrict__ W,
                                              const float* __restrict__ bias,
                                              float* __restrict__ H) {
    __shared__ __align__(16) float As[32][132];   // [k][m], +4 pad
    __shared__ __align__(16) float Bs[32][128];   // [k][n]
    const int t  = threadIdx.x;
    const int m0 = blockIdx.x * 128;
    const int n0 = blockIdx.y * 128;
    const int tx = t & 15;
    const int ty = t >> 4;

    int arow[4], ak4[4], brow[4], bc4[4];
#pragma unroll
    for (int r = 0; r < 4; ++r) {
        int idx = t + r * 256;
        arow[r] = idx >> 3;           // 0..127
        ak4[r]  = (idx & 7) << 2;     // 0..28
        brow[r] = idx >> 5;           // 0..31
        bc4[r]  = (idx & 31) << 2;    // 0..124
    }

    float acc[8][8];
#pragma unroll
    for (int i = 0; i < 8; ++i)
#pragma unroll
        for (int j = 0; j < 8; ++j) acc[i][j] = 0.0f;

    float4 apre[4], bpre[4];
#pragma unroll
    for (int r = 0; r < 4; ++r) {
        apre[r] = *(const float4*)(X + (size_t)(m0 + arow[r]) * IDIM + ak4[r]);
        bpre[r] = *(const float4*)(W + (size_t)brow[r] * HDIM + n0 + bc4[r]);
    }
#pragma unroll
    for (int r = 0; r < 4; ++r) {
        As[ak4[r] + 0][arow[r]] = apre[r].x;
        As[ak4[r] + 1][arow[r]] = apre[r].y;
        As[ak4[r] + 2][arow[r]] = apre[r].z;
        As[ak4[r] + 3][arow[r]] = apre[r].w;
        *(float4*)&Bs[brow[r]][bc4[r]] = bpre[r];
    }
    __syncthreads();

#pragma unroll 1
    for (int kt = 0; kt < 8; ++kt) {
        if (kt < 7) {
            int kn = (kt + 1) * 32;
#pragma unroll
            for (int r = 0; r < 4; ++r) {
                apre[r] = *(const float4*)(X + (size_t)(m0 + arow[r]) * IDIM + kn + ak4[r]);
                bpre[r] = *(const float4*)(W + (size_t)(kn + brow[r]) * HDIM + n0 + bc4[r]);
            }
        }
#pragma unroll 8
        for (int k = 0; k < 32; ++k) {
            float4 a0 = *(const float4*)&As[k][ty * 8];
            float4 a1 = *(const float4*)&As[k][ty * 8 + 4];
            float4 b0 = *(const float4*)&Bs[k][tx * 4];
            float4 b1 = *(const float4*)&Bs[k][tx * 4 + 64];
            float av[8] = {a0.x, a0.y, a0.z, a0.w, a1.x, a1.y, a1.z, a1.w};
            float bv[8] = {b0.x, b0.y, b0.z, b0.w, b1.x, b1.y, b1.z, b1.w};
#pragma unroll
            for (int i = 0; i < 8; ++i)
#pragma unroll
                for (int j = 0; j < 8; ++j)
                    acc[i][j] = fmaf(av[i], bv[j], acc[i][j]);
        }
        __syncthreads();
        if (kt < 7) {
#pragma unroll
            for (int r = 0; r < 4; ++r) {
                As[ak4[r] + 0][arow[r]] = apre[r].x;
                As[ak4[r] + 1][arow[r]] = apre[r].y;
                As[ak4[r] + 2][arow[r]] = apre[r].z;
                As[ak4[r] + 3][arow[r]] = apre[r].w;
                *(float4*)&Bs[brow[r]][bc4[r]] = bpre[r];
            }
            __syncthreads();
        }
    }

#pragma unroll
    for (int i = 0; i < 8; ++i) {
        int gm = m0 + ty * 8 + i;
        float* o = H + (size_t)gm * HDIM + n0;
        float4 v0, v1;
        v0.x = acc[i][0] + bias[n0 + tx * 4 + 0];
        v0.y = acc[i][1] + bias[n0 + tx * 4 + 1];
        v0.z = acc[i][2] + bias[n0 + tx * 4 + 2];
        v0.w = acc[i][3] + bias[n0 + tx * 4 + 3];
        v1.x = acc[i][4] + bias[n0 + 64 + tx * 4 + 0];
        v1.y = acc[i][5] + bias[n0 + 64 + tx * 4 + 1];
        v1.z = acc[i][6] + bias[n0 + 64 + tx * 4 + 2];
        v1.w = acc[i][7] + bias[n0 + 64 + tx * 4 + 3];
        *(float4*)(o + tx * 4) = v0;
        *(float4*)(o + 64 + tx * 4) = v1;
    }
}

// ---------------------------------------------------------------------------
// K2: per-row top-128/top-256 by energy. Single 512-bin histogram on
// (u>>19)-1600 (exponent + 4 mantissa bits: equal u => equal bin, ~10-25
// elems/bin near threshold), shared by both k; exact rank among boundary-bin
// candidates with packed (u, 1023-idx) keys; binary-search fallback.
// ---------------------------------------------------------------------------
#define NBIN 512
#define KBASE 1600
#define CAP 128

__device__ __forceinline__ unsigned int bsearch_kth(const unsigned int* u, int k,
                                                    int lane, int* r_out) {
    unsigned long long lo = 0, hi = 0xFFFFFFFFull;
    while (lo < hi) {
        unsigned int mid = (unsigned int)((lo + hi + 1) >> 1);
        int c = 0;
#pragma unroll
        for (int i = 0; i < 16; ++i) c += (u[i] >= mid) ? 1 : 0;
#pragma unroll
        for (int off = 1; off < 64; off <<= 1) {
            int o = __shfl_down(c, off, 64);
            if (lane + off < 64) c += o;
        }
        c = __shfl(c, 0);
        if (c >= k) lo = mid; else hi = (unsigned long long)mid - 1;
    }
    unsigned int T = (unsigned int)lo;
    int g = 0;
#pragma unroll
    for (int i = 0; i < 16; ++i) g += (u[i] > T) ? 1 : 0;
#pragma unroll
    for (int off = 1; off < 64; off <<= 1) {
        int o = __shfl_down(g, off, 64);
        if (lane + off < 64) g += o;
    }
    g = __shfl(g, 0);
    *r_out = k - g;
    return T;
}

__global__ __launch_bounds__(256) void k2_topk(const float* __restrict__ mask_prev,
                                               float* __restrict__ Hio,
                                               __hip_bfloat16* __restrict__ Abf) {
    __shared__ unsigned int hist[4][NBIN];
    __shared__ unsigned long long cand[4][2][CAP];
    __shared__ unsigned int sres[4][8];   // b1,kk1,b2,kk2, T1,g1, T2,g2
    __shared__ unsigned int scnt[4][2];
    const int t = threadIdx.x;
    const int wave = t >> 6;
    const int lane = t & 63;
    const size_t row = (size_t)blockIdx.x * 4 + wave;
    const float* mp = mask_prev + row * HDIM;
    float* hrow = Hio + row * HDIM;

    float hv[16], mpv[16];
    unsigned int u[16];
    int bin[16];
#pragma unroll
    for (int i = 0; i < 16; ++i) {
        int j = lane + (i << 6);
        float m = mp[j];
        float h = hrow[j];
        h = (m > 0.0f) ? 0.0f : h;
        mpv[i] = m; hv[i] = h;
        float e = h * h;
        u[i] = __float_as_uint(e);
        int b = (int)(u[i] >> 19) - KBASE;
        bin[i] = (b < 0) ? 0 : ((b > NBIN - 1) ? NBIN - 1 : b);
    }

    // zero + histogram
#pragma unroll
    for (int q = 0; q < 8; ++q) hist[wave][lane + (q << 6)] = 0u;
    if (lane < 2) scnt[wave][lane] = 0u;
    __syncthreads();
#pragma unroll
    for (int i = 0; i < 16; ++i) atomicAdd(&hist[wave][bin[i]], 1u);
    __syncthreads();

    // combined scan for k=128 and k=256 (descending bins)
    {
        unsigned int cj[8]; unsigned int lt = 0;
#pragma unroll
        for (int jj = 0; jj < 8; ++jj) { cj[jj] = hist[wave][lane * 8 + jj]; lt += cj[jj]; }
        unsigned int s = lt;
#pragma unroll
        for (int off = 1; off < 64; off <<= 1) {
            unsigned int o = (unsigned int)__shfl_down((int)s, off, 64);
            if (lane + off < 64) s += o;
        }
        unsigned int run = s - lt;    // count in bins above my top bin
#pragma unroll
        for (int jj = 7; jj >= 0; --jj) {
            unsigned int gt = run, ge = run + cj[jj];
            if (gt < CDIM && CDIM <= ge)         { sres[wave][0] = lane * 8 + jj; sres[wave][1] = CDIM - gt; }
            if (gt < 2 * CDIM && 2 * CDIM <= ge) { sres[wave][2] = lane * 8 + jj; sres[wave][3] = 2 * CDIM - gt; }
            run = ge;
        }
    }
    __syncthreads();
    const unsigned int b1 = sres[wave][0], kk1 = sres[wave][1];
    const unsigned int b2 = sres[wave][2], kk2 = sres[wave][3];

    // gather boundary-bin candidates
#pragma unroll
    for (int i = 0; i < 16; ++i) {
        int j = lane + (i << 6);
        unsigned long long pk = ((unsigned long long)u[i] << 32) | (unsigned int)(1023 - j);
        if ((unsigned int)bin[i] == b1) {
            unsigned int p = atomicAdd(&scnt[wave][0], 1u);
            if (p < CAP) cand[wave][0][p] = pk;
        }
        if (b2 != b1 && (unsigned int)bin[i] == b2) {
            unsigned int p = atomicAdd(&scnt[wave][1], 1u);
            if (p < CAP) cand[wave][1][p] = pk;
        }
    }
    __syncthreads();
    const unsigned int C1 = scnt[wave][0];
    const unsigned int C2 = (b2 == b1) ? C1 : scnt[wave][1];
    const unsigned long long* L2 = (b2 == b1) ? cand[wave][0] : cand[wave][1];

    // exact rank within boundary bin
    if (C1 <= CAP) {
        for (unsigned int idx = lane; idx < C1; idx += 64) {
            unsigned long long mine = cand[wave][0][idx];
            unsigned int myu = (unsigned int)(mine >> 32);
            unsigned int rank = 0, gtu = 0;
            for (unsigned int c = 0; c < C1; ++c) {
                unsigned long long o = cand[wave][0][c];
                rank += (o > mine) ? 1u : 0u;
                gtu  += ((unsigned int)(o >> 32) > myu) ? 1u : 0u;
            }
            if (rank == kk1 - 1) { sres[wave][4] = myu; sres[wave][5] = gtu; }
        }
    }
    if (C2 <= CAP) {
        for (unsigned int idx = lane; idx < C2; idx += 64) {
            unsigned long long mine = L2[idx];
            unsigned int myu = (unsigned int)(mine >> 32);
            unsigned int rank = 0, gtu = 0;
            for (unsigned int c = 0; c < C2; ++c) {
                unsigned long long o = L2[c];
                rank += (o > mine) ? 1u : 0u;
                gtu  += ((unsigned int)(o >> 32) > myu) ? 1u : 0u;
            }
            if (rank == kk2 - 1) { sres[wave][6] = myu; sres[wave][7] = gtu; }
        }
    }
    __syncthreads();

    unsigned int T1, T2; int r1, r2;
    if (C1 <= CAP) { T1 = sres[wave][4]; r1 = (int)(kk1 - sres[wave][5]); }
    else           { T1 = bsearch_kth(u, CDIM, lane, &r1); }
    if (C2 <= CAP) { T2 = sres[wave][6]; r2 = (int)(kk2 - sres[wave][7]); }
    else           { T2 = bsearch_kth(u, 2 * CDIM, lane, &r2); }

    // final selection + writes (index-ascending tie break)
    const unsigned long long below = (1ULL << lane) - 1ULL;
    int c1 = 0, c2 = 0;
#pragma unroll
    for (int i = 0; i < 16; ++i) {
        unsigned long long bb1 = __ballot(u[i] == T1);
        unsigned long long bb2 = __ballot(u[i] == T2);
        bool s1 = (u[i] > T1) || ((u[i] == T1) && (c1 + (int)__popcll(bb1 & below) < r1));
        bool s2 = (u[i] > T2) || ((u[i] == T2) && (c2 + (int)__popcll(bb2 & below) < r2));
        c1 += (int)__popcll(bb1);
        c2 += (int)__popcll(bb2);
        int j = lane + (i << 6);
        hrow[j] = mpv[i] + (s1 ? 1.0f : 0.0f);
        Abf[row * HDIM + j] = __float2bfloat16(s2 ? hv[i] : 0.0f);
    }
}

// ---------------------------------------------------------------------------
// K3: decoder GEMM bf16 MFMA, 128x128 tile, BK=32. LDS row stride padded to
// 40 shorts (80B) so frag ds_read_b128 starts cycle 8 bank groups (2-way ==
// free) instead of aliasing to banks {0,16} (8-way). Register prefetch.
// ---------------------------------------------------------------------------
#define K3LD 40
__global__ __launch_bounds__(256) void k3_dec(const __hip_bfloat16* __restrict__ A,
                                              const __hip_bfloat16* __restrict__ Bt,
                                              const float* __restrict__ bias_self,
                                              const float* __restrict__ bias_src,
                                              const int* __restrict__ dtype,
                                              float* __restrict__ Out) {
    __shared__ __align__(16) __hip_bfloat16 As[128 * K3LD];
    __shared__ __align__(16) __hip_bfloat16 Bs[128 * K3LD];
    const int t = threadIdx.x;
    const int lane = t & 63;
    const int wave = t >> 6;
    const int m0 = blockIdx.x * 128;
    const int n0 = blockIdx.y * 128;
    const int wr = wave >> 1;
    const int wc = wave & 1;
    const int quad = lane >> 4;
    const int rf = lane & 15;

    int srow[2], skc[2];
#pragma unroll
    for (int p = 0; p < 2; ++p) {
        int l = p * 256 + t;
        srow[p] = l >> 2;
        skc[p]  = (l & 3) << 3;
    }

    floatx4 acc[4][4];
    const floatx4 z = {0.0f, 0.0f, 0.0f, 0.0f};
#pragma unroll
    for (int i = 0; i < 4; ++i)
#pragma unroll
        for (int j = 0; j < 4; ++j) acc[i][j] = z;

    uint4 apre[2], bpre[2];
#pragma unroll
    for (int p = 0; p < 2; ++p) {
        apre[p] = *(const uint4*)(A  + (size_t)(m0 + srow[p]) * HDIM + skc[p]);
        bpre[p] = *(const uint4*)(Bt + (size_t)(n0 + srow[p]) * HDIM + skc[p]);
    }
#pragma unroll
    for (int p = 0; p < 2; ++p) {
        *(uint4*)&As[srow[p] * K3LD + skc[p]] = apre[p];
        *(uint4*)&Bs[srow[p] * K3LD + skc[p]] = bpre[p];
    }
    __syncthreads();

#pragma unroll 1
    for (int kt = 0; kt < HDIM / 32; ++kt) {
        if (kt < HDIM / 32 - 1) {
            int kn = (kt + 1) * 32;
#pragma unroll
            for (int p = 0; p < 2; ++p) {
                apre[p] = *(const uint4*)(A  + (size_t)(m0 + srow[p]) * HDIM + kn + skc[p]);
                bpre[p] = *(const uint4*)(Bt + (size_t)(n0 + srow[p]) * HDIM + kn + skc[p]);
            }
        }
        shortx8 af[4], bf[4];
#pragma unroll
        for (int i = 0; i < 4; ++i) {
            af[i] = *(const shortx8*)&As[(wr * 64 + i * 16 + rf) * K3LD + quad * 8];
            bf[i] = *(const shortx8*)&Bs[(wc * 64 + i * 16 + rf) * K3LD + quad * 8];
        }
#pragma unroll
        for (int mi = 0; mi < 4; ++mi)
#pragma unroll
            for (int nj = 0; nj < 4; ++nj)
                acc[mi][nj] = __builtin_amdgcn_mfma_f32_16x16x32_bf16(
                    af[mi], bf[nj], acc[mi][nj], 0, 0, 0);
        __syncthreads();
        if (kt < HDIM / 32 - 1) {
#pragma unroll
            for (int p = 0; p < 2; ++p) {
                *(uint4*)&As[srow[p] * K3LD + skc[p]] = apre[p];
                *(uint4*)&Bs[srow[p] * K3LD + skc[p]] = bpre[p];
            }
            __syncthreads();
        }
    }

    const float* bias = (*dtype == 0) ? bias_self : bias_src;
#pragma unroll
    for (int mi = 0; mi < 4; ++mi) {
#pragma unroll
        for (int nj = 0; nj < 4; ++nj) {
            int gn = n0 + wc * 64 + nj * 16 + rf;
            float bv = bias[gn];
            int gmb = m0 + wr * 64 + mi * 16 + quad * 4;
#pragma unroll
            for (int r2 = 0; r2 < 4; ++r2)
                Out[(size_t)(gmb + r2) * ODIM + gn] = acc[mi][nj][r2] + bv;
        }
    }
}

// ---------------------------------------------------------------------------
extern "C" void kernel_launch(void* const* d_in, const int* in_sizes, int n_in,
                              void* d_out, int out_size, void* d_ws, size_t ws_size,
                              hipStream_t stream) {
    const float* x          = (const float*)d_in[0];
    const float* mask_prev  = (const float*)d_in[1];
    const float* W_enc      = (const float*)d_in[2];
    const float* b_enc      = (const float*)d_in[3];
    const float* W_dec_self = (const float*)d_in[4];
    const float* b_dec_self = (const float*)d_in[5];
    const float* W_dec_src  = (const float*)d_in[6];
    const float* b_dec_src  = (const float*)d_in[7];
    const int*   dtype      = (const int*)d_in[8];

    float* out  = (float*)d_out;
    float* Hbuf = out + OUT_OFF;   // h staged in mask_new output region (in-place per row)

    __hip_bfloat16* Abf = (__hip_bfloat16*)d_ws;                             // 128 MB
    __hip_bfloat16* WdT = (__hip_bfloat16*)((char*)d_ws + (size_t)M_ * HDIM * 2);

    k0_convw<<<dim3((ODIM * HDIM) / 256), 256, 0, stream>>>(W_dec_self, W_dec_src, dtype, WdT);
    k1_enc  <<<dim3(M_ / 128, HDIM / 128), 256, 0, stream>>>(x, W_enc, b_enc, Hbuf);
    k2_topk <<<dim3(M_ / 4), 256, 0, stream>>>(mask_prev, Hbuf, Abf);
    k3_dec  <<<dim3(M_ / 128, ODIM / 128), 256, 0, stream>>>(Abf, WdT, b_dec_self, b_dec_src, dtype, out);
}

// Round 3
// 1162.656 us; speedup vs baseline: 1.0208x; 1.0208x over previous
//
#include <hip/hip_runtime.h>
#include <hip/hip_bf16.h>

#define B_ 8
#define T_ 8192
#define M_ (B_ * T_)          // 65536 rows
#define IDIM 256
#define HDIM 1024
#define ODIM 256
#define CDIM 128
#define OUT_OFF ((size_t)M_ * ODIM)   // start of mask_new region in d_out

typedef __attribute__((ext_vector_type(4))) float floatx4;
typedef __attribute__((ext_vector_type(8))) short shortx8;

// ---------------------------------------------------------------------------
// K0: WdT[n][k] = bf16(W_dec_sel[k][n])
// ---------------------------------------------------------------------------
__global__ __launch_bounds__(256) void k0_convw(const float* __restrict__ Wself,
                                                const float* __restrict__ Wsrc,
                                                const int* __restrict__ dtype,
                                                __hip_bfloat16* __restrict__ WdT) {
    int id = blockIdx.x * 256 + threadIdx.x;
    int n = id >> 10;
    int k = id & 1023;
    const float* W = (*dtype == 0) ? Wself : Wsrc;
    WdT[id] = __float2bfloat16(W[(size_t)k * ODIM + n]);
}

// ---------------------------------------------------------------------------
// K1: encoder GEMM fp32 (must be fp32: top-k selection sensitivity).
// BM=128 BN=128 BK=32, 256 threads, 8x8 micro-tile.
// NOTE: round-2 register prefetch regressed this (VGPR 64->100, occ 40->23%,
// 398->472us) -- reverted to the 64-VGPR round-1 form.
// ---------------------------------------------------------------------------
__global__ __launch_bounds__(256) void k1_enc(const float* __restrict__ X,
                                              const float* __restrict__ W,
                                              const float* __restrict__ bias,
                                              float* __restrict__ H) {
    __shared__ __align__(16) float As[32][132];   // [k][m], +4 pad
    __shared__ __align__(16) float Bs[32][128];   // [k][n]
    const int t  = threadIdx.x;
    const int m0 = blockIdx.x * 128;
    const int n0 = blockIdx.y * 128;
    const int tx = t & 15;
    const int ty = t >> 4;

    float acc[8][8];
#pragma unroll
    for (int i = 0; i < 8; ++i)
#pragma unroll
        for (int j = 0; j < 8; ++j) acc[i][j] = 0.0f;

    for (int kk = 0; kk < IDIM; kk += 32) {
#pragma unroll
        for (int r = 0; r < 4; ++r) {
            int idx = t + r * 256;
            int row = idx >> 3;
            int k4  = (idx & 7) << 2;
            float4 a = *(const float4*)(X + (size_t)(m0 + row) * IDIM + kk + k4);
            As[k4 + 0][row] = a.x;
            As[k4 + 1][row] = a.y;
            As[k4 + 2][row] = a.z;
            As[k4 + 3][row] = a.w;
        }
#pragma unroll
        for (int r = 0; r < 4; ++r) {
            int idx = t + r * 256;
            int row = idx >> 5;
            int c4  = (idx & 31) << 2;
            *(float4*)&Bs[row][c4] =
                *(const float4*)(W + (size_t)(kk + row) * HDIM + n0 + c4);
        }
        __syncthreads();

#pragma unroll 8
        for (int k = 0; k < 32; ++k) {
            float4 a0 = *(const float4*)&As[k][ty * 8];
            float4 a1 = *(const float4*)&As[k][ty * 8 + 4];
            float4 b0 = *(const float4*)&Bs[k][tx * 4];
            float4 b1 = *(const float4*)&Bs[k][tx * 4 + 64];
            float av[8] = {a0.x, a0.y, a0.z, a0.w, a1.x, a1.y, a1.z, a1.w};
            float bv[8] = {b0.x, b0.y, b0.z, b0.w, b1.x, b1.y, b1.z, b1.w};
#pragma unroll
            for (int i = 0; i < 8; ++i)
#pragma unroll
                for (int j = 0; j < 8; ++j)
                    acc[i][j] = fmaf(av[i], bv[j], acc[i][j]);
        }
        __syncthreads();
    }

#pragma unroll
    for (int i = 0; i < 8; ++i) {
        int gm = m0 + ty * 8 + i;
        float* o = H + (size_t)gm * HDIM + n0;
        float4 v0, v1;
        v0.x = acc[i][0] + bias[n0 + tx * 4 + 0];
        v0.y = acc[i][1] + bias[n0 + tx * 4 + 1];
        v0.z = acc[i][2] + bias[n0 + tx * 4 + 2];
        v0.w = acc[i][3] + bias[n0 + tx * 4 + 3];
        v1.x = acc[i][4] + bias[n0 + 64 + tx * 4 + 0];
        v1.y = acc[i][5] + bias[n0 + 64 + tx * 4 + 1];
        v1.z = acc[i][6] + bias[n0 + 64 + tx * 4 + 2];
        v1.w = acc[i][7] + bias[n0 + 64 + tx * 4 + 3];
        *(float4*)(o + tx * 4) = v0;
        *(float4*)(o + 64 + tx * 4) = v1;
    }
}

// ---------------------------------------------------------------------------
// K2: per-row top-128/top-256 by energy, fully vectorized memory access:
// lane owns contiguous 16 elements (j = lane*16 + i). float4 loads/stores,
// uint4 (8x bf16) stores. Histogram on (u>>19)-KBASE (equal u => equal bin);
// exact rank among boundary-bin candidates via packed (u, 1023-j) keys;
// binary-search fallback. Tie-break = index-ascending, implemented with
// per-lane prefix + cross-lane shfl_up scan for the (lane,i) index order.
// ---------------------------------------------------------------------------
#define NBIN 512
#define KBASE 1600
#define CAP 128

__device__ __forceinline__ unsigned int bsearch_kth(const unsigned int* u, int k,
                                                    int lane, int* r_out) {
    unsigned long long lo = 0, hi = 0xFFFFFFFFull;
    while (lo < hi) {
        unsigned int mid = (unsigned int)((lo + hi + 1) >> 1);
        int c = 0;
#pragma unroll
        for (int i = 0; i < 16; ++i) c += (u[i] >= mid) ? 1 : 0;
#pragma unroll
        for (int off = 1; off < 64; off <<= 1) {
            int o = __shfl_down(c, off, 64);
            if (lane + off < 64) c += o;
        }
        c = __shfl(c, 0);
        if (c >= k) lo = mid; else hi = (unsigned long long)mid - 1;
    }
    unsigned int T = (unsigned int)lo;
    int g = 0;
#pragma unroll
    for (int i = 0; i < 16; ++i) g += (u[i] > T) ? 1 : 0;
#pragma unroll
    for (int off = 1; off < 64; off <<= 1) {
        int o = __shfl_down(g, off, 64);
        if (lane + off < 64) g += o;
    }
    g = __shfl(g, 0);
    *r_out = k - g;
    return T;
}

__global__ __launch_bounds__(256) void k2_topk(const float* __restrict__ mask_prev,
                                               float* __restrict__ Hio,
                                               __hip_bfloat16* __restrict__ Abf) {
    __shared__ unsigned int hist[4][NBIN];
    __shared__ unsigned long long cand[4][2][CAP];
    __shared__ unsigned int sres[4][8];   // b1,kk1,b2,kk2, T1,g1, T2,g2
    __shared__ unsigned int scnt[4][2];
    const int t = threadIdx.x;
    const int wave = t >> 6;
    const int lane = t & 63;
    const size_t row = (size_t)blockIdx.x * 4 + wave;
    const float* mp = mask_prev + row * HDIM + lane * 16;
    float* hrow = Hio + row * HDIM + lane * 16;

    float hv[16], mpv[16];
    unsigned int u[16];
    int bin[16];
#pragma unroll
    for (int c = 0; c < 4; ++c) {
        float4 m4 = *(const float4*)(mp + c * 4);
        float4 h4 = *(const float4*)(hrow + c * 4);
        float mm[4] = {m4.x, m4.y, m4.z, m4.w};
        float hh[4] = {h4.x, h4.y, h4.z, h4.w};
#pragma unroll
        for (int x = 0; x < 4; ++x) {
            int i = c * 4 + x;
            float h = (mm[x] > 0.0f) ? 0.0f : hh[x];
            mpv[i] = mm[x]; hv[i] = h;
            u[i] = __float_as_uint(h * h);
            int b = (int)(u[i] >> 19) - KBASE;
            bin[i] = (b < 0) ? 0 : ((b > NBIN - 1) ? NBIN - 1 : b);
        }
    }

    // zero + histogram
#pragma unroll
    for (int q = 0; q < 8; ++q) hist[wave][lane + (q << 6)] = 0u;
    if (lane < 2) scnt[wave][lane] = 0u;
    __syncthreads();
#pragma unroll
    for (int i = 0; i < 16; ++i) atomicAdd(&hist[wave][bin[i]], 1u);
    __syncthreads();

    // combined scan for k=128 and k=256 (descending bins)
    {
        unsigned int cj[8]; unsigned int lt = 0;
#pragma unroll
        for (int jj = 0; jj < 8; ++jj) { cj[jj] = hist[wave][lane * 8 + jj]; lt += cj[jj]; }
        unsigned int s = lt;
#pragma unroll
        for (int off = 1; off < 64; off <<= 1) {
            unsigned int o = (unsigned int)__shfl_down((int)s, off, 64);
            if (lane + off < 64) s += o;
        }
        unsigned int run = s - lt;    // count in bins above my top bin
#pragma unroll
        for (int jj = 7; jj >= 0; --jj) {
            unsigned int gt = run, ge = run + cj[jj];
            if (gt < CDIM && CDIM <= ge)         { sres[wave][0] = lane * 8 + jj; sres[wave][1] = CDIM - gt; }
            if (gt < 2 * CDIM && 2 * CDIM <= ge) { sres[wave][2] = lane * 8 + jj; sres[wave][3] = 2 * CDIM - gt; }
            run = ge;
        }
    }
    __syncthreads();
    const unsigned int b1 = sres[wave][0], kk1 = sres[wave][1];
    const unsigned int b2 = sres[wave][2], kk2 = sres[wave][3];

    // gather boundary-bin candidates (j = lane*16 + i)
#pragma unroll
    for (int i = 0; i < 16; ++i) {
        int j = lane * 16 + i;
        unsigned long long pk = ((unsigned long long)u[i] << 32) | (unsigned int)(1023 - j);
        if ((unsigned int)bin[i] == b1) {
            unsigned int p = atomicAdd(&scnt[wave][0], 1u);
            if (p < CAP) cand[wave][0][p] = pk;
        }
        if (b2 != b1 && (unsigned int)bin[i] == b2) {
            unsigned int p = atomicAdd(&scnt[wave][1], 1u);
            if (p < CAP) cand[wave][1][p] = pk;
        }
    }
    __syncthreads();
    const unsigned int C1 = scnt[wave][0];
    const unsigned int C2 = (b2 == b1) ? C1 : scnt[wave][1];
    const unsigned long long* L2 = (b2 == b1) ? cand[wave][0] : cand[wave][1];

    // exact rank within boundary bin
    if (C1 <= CAP) {
        for (unsigned int idx = lane; idx < C1; idx += 64) {
            unsigned long long mine = cand[wave][0][idx];
            unsigned int myu = (unsigned int)(mine >> 32);
            unsigned int rank = 0, gtu = 0;
            for (unsigned int c = 0; c < C1; ++c) {
                unsigned long long o = cand[wave][0][c];
                rank += (o > mine) ? 1u : 0u;
                gtu  += ((unsigned int)(o >> 32) > myu) ? 1u : 0u;
            }
            if (rank == kk1 - 1) { sres[wave][4] = myu; sres[wave][5] = gtu; }
        }
    }
    if (C2 <= CAP) {
        for (unsigned int idx = lane; idx < C2; idx += 64) {
            unsigned long long mine = L2[idx];
            unsigned int myu = (unsigned int)(mine >> 32);
            unsigned int rank = 0, gtu = 0;
            for (unsigned int c = 0; c < C2; ++c) {
                unsigned long long o = L2[c];
                rank += (o > mine) ? 1u : 0u;
                gtu  += ((unsigned int)(o >> 32) > myu) ? 1u : 0u;
            }
            if (rank == kk2 - 1) { sres[wave][6] = myu; sres[wave][7] = gtu; }
        }
    }
    __syncthreads();

    unsigned int T1, T2; int r1, r2;
    if (C1 <= CAP) { T1 = sres[wave][4]; r1 = (int)(kk1 - sres[wave][5]); }
    else           { T1 = bsearch_kth(u, CDIM, lane, &r1); }
    if (C2 <= CAP) { T2 = sres[wave][6]; r2 = (int)(kk2 - sres[wave][7]); }
    else           { T2 = bsearch_kth(u, 2 * CDIM, lane, &r2); }

    // tie ranks for (lane, i) ascending-index order:
    // rank = (#equal in lanes < me) + (#equal in my lane with i' < i)
    int p1[16], p2[16];
    int tot1 = 0, tot2 = 0;
#pragma unroll
    for (int i = 0; i < 16; ++i) {
        p1[i] = tot1; p2[i] = tot2;
        tot1 += (u[i] == T1) ? 1 : 0;
        tot2 += (u[i] == T2) ? 1 : 0;
    }
    int s1v = tot1, s2v = tot2;
#pragma unroll
    for (int off = 1; off < 64; off <<= 1) {
        int o1 = __shfl_up(s1v, off, 64);
        int o2 = __shfl_up(s2v, off, 64);
        if (lane >= off) { s1v += o1; s2v += o2; }
    }
    const int ex1 = s1v - tot1;
    const int ex2 = s2v - tot2;

    // mask_new store: 4x float4
#pragma unroll
    for (int c = 0; c < 4; ++c) {
        float v[4];
#pragma unroll
        for (int x = 0; x < 4; ++x) {
            int i = c * 4 + x;
            bool s1 = (u[i] > T1) || ((u[i] == T1) && (ex1 + p1[i] < r1));
            v[x] = mpv[i] + (s1 ? 1.0f : 0.0f);
        }
        float4 v4 = {v[0], v[1], v[2], v[3]};
        *(float4*)(hrow + c * 4) = v4;
    }
    // Abf store: 2x uint4 (8 bf16 each)
    __hip_bfloat16* ab = Abf + row * HDIM + lane * 16;
#pragma unroll
    for (int half = 0; half < 2; ++half) {
        union { unsigned short us[8]; uint4 v; } pk;
#pragma unroll
        for (int x = 0; x < 8; ++x) {
            int i = half * 8 + x;
            bool s2 = (u[i] > T2) || ((u[i] == T2) && (ex2 + p2[i] < r2));
            __hip_bfloat16 bb = __float2bfloat16(s2 ? hv[i] : 0.0f);
            pk.us[x] = *(unsigned short*)&bb;
        }
        *(uint4*)(ab + half * 8) = pk.v;
    }
}

// ---------------------------------------------------------------------------
// K3: decoder GEMM bf16 MFMA, 128x128 tile, BK=32, padded LDS (K3LD=40),
// register prefetch (unchanged from round 2).
// ---------------------------------------------------------------------------
#define K3LD 40
__global__ __launch_bounds__(256) void k3_dec(const __hip_bfloat16* __restrict__ A,
                                              const __hip_bfloat16* __restrict__ Bt,
                                              const float* __restrict__ bias_self,
                                              const float* __restrict__ bias_src,
                                              const int* __restrict__ dtype,
                                              float* __restrict__ Out) {
    __shared__ __align__(16) __hip_bfloat16 As[128 * K3LD];
    __shared__ __align__(16) __hip_bfloat16 Bs[128 * K3LD];
    const int t = threadIdx.x;
    const int lane = t & 63;
    const int wave = t >> 6;
    const int m0 = blockIdx.x * 128;
    const int n0 = blockIdx.y * 128;
    const int wr = wave >> 1;
    const int wc = wave & 1;
    const int quad = lane >> 4;
    const int rf = lane & 15;

    int srow[2], skc[2];
#pragma unroll
    for (int p = 0; p < 2; ++p) {
        int l = p * 256 + t;
        srow[p] = l >> 2;
        skc[p]  = (l & 3) << 3;
    }

    floatx4 acc[4][4];
    const floatx4 z = {0.0f, 0.0f, 0.0f, 0.0f};
#pragma unroll
    for (int i = 0; i < 4; ++i)
#pragma unroll
        for (int j = 0; j < 4; ++j) acc[i][j] = z;

    uint4 apre[2], bpre[2];
#pragma unroll
    for (int p = 0; p < 2; ++p) {
        apre[p] = *(const uint4*)(A  + (size_t)(m0 + srow[p]) * HDIM + skc[p]);
        bpre[p] = *(const uint4*)(Bt + (size_t)(n0 + srow[p]) * HDIM + skc[p]);
    }
#pragma unroll
    for (int p = 0; p < 2; ++p) {
        *(uint4*)&As[srow[p] * K3LD + skc[p]] = apre[p];
        *(uint4*)&Bs[srow[p] * K3LD + skc[p]] = bpre[p];
    }
    __syncthreads();

#pragma unroll 1
    for (int kt = 0; kt < HDIM / 32; ++kt) {
        if (kt < HDIM / 32 - 1) {
            int kn = (kt + 1) * 32;
#pragma unroll
            for (int p = 0; p < 2; ++p) {
                apre[p] = *(const uint4*)(A  + (size_t)(m0 + srow[p]) * HDIM + kn + skc[p]);
                bpre[p] = *(const uint4*)(Bt + (size_t)(n0 + srow[p]) * HDIM + kn + skc[p]);
            }
        }
        shortx8 af[4], bf[4];
#pragma unroll
        for (int i = 0; i < 4; ++i) {
            af[i] = *(const shortx8*)&As[(wr * 64 + i * 16 + rf) * K3LD + quad * 8];
            bf[i] = *(const shortx8*)&Bs[(wc * 64 + i * 16 + rf) * K3LD + quad * 8];
        }
#pragma unroll
        for (int mi = 0; mi < 4; ++mi)
#pragma unroll
            for (int nj = 0; nj < 4; ++nj)
                acc[mi][nj] = __builtin_amdgcn_mfma_f32_16x16x32_bf16(
                    af[mi], bf[nj], acc[mi][nj], 0, 0, 0);
        __syncthreads();
        if (kt < HDIM / 32 - 1) {
#pragma unroll
            for (int p = 0; p < 2; ++p) {
                *(uint4*)&As[srow[p] * K3LD + skc[p]] = apre[p];
                *(uint4*)&Bs[srow[p] * K3LD + skc[p]] = bpre[p];
            }
            __syncthreads();
        }
    }

    const float* bias = (*dtype == 0) ? bias_self : bias_src;
#pragma unroll
    for (int mi = 0; mi < 4; ++mi) {
#pragma unroll
        for (int nj = 0; nj < 4; ++nj) {
            int gn = n0 + wc * 64 + nj * 16 + rf;
            float bv = bias[gn];
            int gmb = m0 + wr * 64 + mi * 16 + quad * 4;
#pragma unroll
            for (int r2 = 0; r2 < 4; ++r2)
                Out[(size_t)(gmb + r2) * ODIM + gn] = acc[mi][nj][r2] + bv;
        }
    }
}

// ---------------------------------------------------------------------------
extern "C" void kernel_launch(void* const* d_in, const int* in_sizes, int n_in,
                              void* d_out, int out_size, void* d_ws, size_t ws_size,
                              hipStream_t stream) {
    const float* x          = (const float*)d_in[0];
    const float* mask_prev  = (const float*)d_in[1];
    const float* W_enc      = (const float*)d_in[2];
    const float* b_enc      = (const float*)d_in[3];
    const float* W_dec_self = (const float*)d_in[4];
    const float* b_dec_self = (const float*)d_in[5];
    const float* W_dec_src  = (const float*)d_in[6];
    const float* b_dec_src  = (const float*)d_in[7];
    const int*   dtype      = (const int*)d_in[8];

    float* out  = (float*)d_out;
    float* Hbuf = out + OUT_OFF;   // h staged in mask_new output region (in-place per row)

    __hip_bfloat16* Abf = (__hip_bfloat16*)d_ws;                             // 128 MB
    __hip_bfloat16* WdT = (__hip_bfloat16*)((char*)d_ws + (size_t)M_ * HDIM * 2);

    k0_convw<<<dim3((ODIM * HDIM) / 256), 256, 0, stream>>>(W_dec_self, W_dec_src, dtype, WdT);
    k1_enc  <<<dim3(M_ / 128, HDIM / 128), 256, 0, stream>>>(x, W_enc, b_enc, Hbuf);
    k2_topk <<<dim3(M_ / 4), 256, 0, stream>>>(mask_prev, Hbuf, Abf);
    k3_dec  <<<dim3(M_ / 128, ODIM / 128), 256, 0, stream>>>(Abf, WdT, b_dec_self, b_dec_src, dtype, out);
}